// Round 8
// baseline (160.902 us; speedup 1.0000x reference)
//
#include <hip/hip_runtime.h>
#include <hip/hip_bf16.h>
#include <math.h>

// FFM: B=32768, n=512, f=30, k=40
// inter[b] = X[b]^T W X[b],  W = 0.5*(C - diag(C)), C symmetric
// out = sigmoid(X@w1 + b + inter)
//
// R8: register-B K-loop (AITER shape). As = 64x512 bf16 swizzled LDS
// (read-only after Phase A); each wave owns a private 32-col strip of W16
// and loads B fragments straight to VGPRs via immediate-offset dwordx4
// loads (compiler emits fine-grained vmcnt). NO barriers in the K-loop.
// 66 KB LDS -> 2 blocks/CU. Linear term folded into Phase A (fp32).
// W-build: coalesced transpose vT + per-row builder (replaces gather-bound
// build_w16).

#define N_FEAT 512
#define FK 1200
#define KDIM 40
#define B_ROWS 32768
#define BM 64

typedef __attribute__((ext_vector_type(8))) short short8;
typedef __attribute__((ext_vector_type(4))) float f32x4;

__device__ __forceinline__ unsigned short bf16_rne(float f) {
    union { float f; unsigned int u; } c; c.f = f;
    unsigned int u = c.u;
    u += 0x7fffu + ((u >> 16) & 1u);
    return (unsigned short)(u >> 16);
}

__device__ __forceinline__ float bf16_to_f(unsigned short h) {
    union { unsigned int u; float f; } c;
    c.u = ((unsigned int)h) << 16;
    return c.f;
}

// ---------------- Kernel 0: transpose v (512 x 1200) -> vT (1200 x 512) ----------------
// Block per column c: scattered reads (L2-resident v), coalesced writes.
__global__ __launch_bounds__(256) void transpose_v(const float* __restrict__ v,
                                                   float* __restrict__ vT) {
    const int c = blockIdx.x;           // 0..1199
    const int i0 = threadIdx.x;
    vT[(size_t)c * N_FEAT + i0]       = v[(size_t)i0 * FK + c];
    vT[(size_t)c * N_FEAT + i0 + 256] = v[(size_t)(i0 + 256) * FK + c];
}

// ---------------- Kernel 1: build W16 (512x512 bf16), coalesced ----------------
// Block per row i. a-operand v[i,:,:] staged in LDS; c-operand vT[f_i*40+q][j]
// is coalesced across j lanes.
__global__ __launch_bounds__(256) void build_w16(const float* __restrict__ v,
                                                 const float* __restrict__ vT,
                                                 const int* __restrict__ f2f,
                                                 unsigned short* __restrict__ W16) {
    __shared__ float vi[FK];
    const int tid = threadIdx.x;
    const int i   = blockIdx.x;         // 0..511

    for (int c = tid; c < FK; c += 256)
        vi[c] = v[(size_t)i * FK + c];
    const int fi = f2f[i];
    const int j0 = tid;
    const int j1 = tid + 256;
    const int fj0 = f2f[j0];
    const int fj1 = f2f[j1];
    __syncthreads();

    const float* base = vT + (size_t)fi * KDIM * N_FEAT;
    float acc0 = 0.f, acc1 = 0.f;
#pragma unroll
    for (int q = 0; q < KDIM; ++q) {
        const float c0 = base[q * N_FEAT + j0];
        const float c1 = base[q * N_FEAT + j1];
        acc0 = fmaf(vi[fj0 * KDIM + q], c0, acc0);
        acc1 = fmaf(vi[fj1 * KDIM + q], c1, acc1);
    }
    W16[(size_t)i * N_FEAT + j0] = (i == j0) ? (unsigned short)0 : bf16_rne(0.5f * acc0);
    W16[(size_t)i * N_FEAT + j1] = (i == j1) ? (unsigned short)0 : bf16_rne(0.5f * acc1);
}

// ---------------- Kernel 2: fused GEMM + quadratic-form epilogue ----------------
// grid: 512 blocks x 256 threads (4 waves). Wave w owns cols cb*128 + w*32
// (2 sixteens), all 64 rows. B frags from global -> registers; no K-loop barriers.
__global__ __launch_bounds__(256, 2) void ffm_fused(const float* __restrict__ X,
                                                    const unsigned short* __restrict__ W16,
                                                    const float* __restrict__ w1,
                                                    const float* __restrict__ bvec,
                                                    float* __restrict__ out) {
    __shared__ __align__(16) unsigned short As[BM * N_FEAT];  // 64 KB, swizzled
    __shared__ float part[4][BM];
    __shared__ float plin[BM];

    const int tid  = threadIdx.x;
    const int lane = tid & 63;
    const int wave = tid >> 6;
    const int quad = lane >> 4;
    const int l16  = lane & 15;
    const int aswz = l16 & 7;

    const size_t row0 = (size_t)blockIdx.x * BM;

    // ---- Phase A: stage As (swizzled) + fp32 linear term per row ----
    {
        const float4* X4 = (const float4*)(X + row0 * N_FEAT);
        const float4 wA = ((const float4*)w1)[lane * 2];
        const float4 wB = ((const float4*)w1)[lane * 2 + 1];
#pragma unroll
        for (int u = 0; u < 16; ++u) {
            const int r  = u * 4 + wave;    // wave-uniform row
            const int cc = lane;            // 16B chunk in row
            float4 f0 = X4[r * 128 + cc * 2];
            float4 f1 = X4[r * 128 + cc * 2 + 1];
            union { unsigned short us[8]; short8 v; } pk;
            pk.us[0] = bf16_rne(f0.x);
            pk.us[1] = bf16_rne(f0.y);
            pk.us[2] = bf16_rne(f0.z);
            pk.us[3] = bf16_rne(f0.w);
            pk.us[4] = bf16_rne(f1.x);
            pk.us[5] = bf16_rne(f1.y);
            pk.us[6] = bf16_rne(f1.z);
            pk.us[7] = bf16_rne(f1.w);
            *(short8*)(As + r * N_FEAT + ((cc ^ (r & 7)) << 3)) = pk.v;
            float lp = f0.x * wA.x + f0.y * wA.y + f0.z * wA.z + f0.w * wA.w
                     + f1.x * wB.x + f1.y * wB.y + f1.z * wB.z + f1.w * wB.w;
#pragma unroll
            for (int off = 1; off < 64; off <<= 1)
                lp += __shfl_xor(lp, off, 64);
            if (lane == 0) plin[r] = lp;
        }
    }
    __syncthreads();   // As ready; no further barriers until reduction

    float rs[4][4];
#pragma unroll
    for (int mi = 0; mi < 4; ++mi)
#pragma unroll
        for (int reg = 0; reg < 4; ++reg) rs[mi][reg] = 0.f;

    for (int cb = 0; cb < 4; ++cb) {
        const int colw = cb * 128 + wave * 32;
        // lane's B base: W16 row (colw + l16), k-offset quad*8
        const unsigned short* wp0 =
            W16 + (((size_t)(colw + l16)) << 9) + (quad << 3);
        const unsigned short* wp1 = wp0 + 16 * N_FEAT;

        f32x4 acc[4][2];
#pragma unroll
        for (int mi = 0; mi < 4; ++mi) {
            acc[mi][0] = (f32x4){0.f, 0.f, 0.f, 0.f};
            acc[mi][1] = (f32x4){0.f, 0.f, 0.f, 0.f};
        }

#pragma unroll 4
        for (int ks = 0; ks < 16; ++ks) {
            const short8 b0 = *(const short8*)(wp0 + ks * 32);   // imm offset 64B*ks
            const short8 b1 = *(const short8*)(wp1 + ks * 32);
            short8 a[4];
            const int kc  = ks * 4 + quad;
            const int off = (kc ^ aswz) << 3;
#pragma unroll
            for (int mi = 0; mi < 4; ++mi)
                a[mi] = *(const short8*)(As + (mi * 16 + l16) * N_FEAT + off);
#pragma unroll
            for (int mi = 0; mi < 4; ++mi) {
                acc[mi][0] = __builtin_amdgcn_mfma_f32_16x16x32_bf16(
                    a[mi], b0, acc[mi][0], 0, 0, 0);
                acc[mi][1] = __builtin_amdgcn_mfma_f32_16x16x32_bf16(
                    a[mi], b1, acc[mi][1], 0, 0, 0);
            }
        }

        // Epilogue for this col-block: rs += x_hat * y  (w1 already in plin).
#pragma unroll
        for (int mi = 0; mi < 4; ++mi) {
#pragma unroll
            for (int ni = 0; ni < 2; ++ni) {
                const int gc = colw + ni * 16 + l16;
#pragma unroll
                for (int reg = 0; reg < 4; ++reg) {
                    const int row = mi * 16 + quad * 4 + reg;
                    const int adr = row * N_FEAT +
                                    ((((gc >> 3) ^ (row & 7)) << 3) | (gc & 7));
                    rs[mi][reg] = fmaf(bf16_to_f(As[adr]), acc[mi][ni][reg],
                                       rs[mi][reg]);
                }
            }
        }
    }

    // Reduce over l16 within each quad, then across the 4 waves via LDS.
#pragma unroll
    for (int mi = 0; mi < 4; ++mi)
#pragma unroll
        for (int reg = 0; reg < 4; ++reg) {
            float r = rs[mi][reg];
#pragma unroll
            for (int off = 1; off < 16; off <<= 1)
                r += __shfl_xor(r, off, 16);
            if (l16 == 0)
                part[wave][mi * 16 + quad * 4 + reg] = r;
        }
    __syncthreads();

    if (tid < BM) {
        const float t = part[0][tid] + part[1][tid] + part[2][tid] + part[3][tid]
                        + plin[tid] + bvec[0];
        out[row0 + tid] = 1.0f / (1.0f + expf(-t));
    }
}

extern "C" void kernel_launch(void* const* d_in, const int* in_sizes, int n_in,
                              void* d_out, int out_size, void* d_ws, size_t ws_size,
                              hipStream_t stream) {
    const float* X   = (const float*)d_in[0];   // 32768 x 512
    const float* w1  = (const float*)d_in[1];   // 512
    const float* b   = (const float*)d_in[2];   // 1
    const float* v   = (const float*)d_in[3];   // 512 x 30 x 40
    const int*   f2f = (const int*)d_in[4];     // 512
    float* out = (float*)d_out;                 // 32768

    unsigned short* W16 = (unsigned short*)d_ws;                       // 512 KB
    float*          vT  = (float*)((char*)d_ws + (1u << 20));          // 2.4 MB

    transpose_v<<<FK, 256, 0, stream>>>(v, vT);
    build_w16<<<N_FEAT, 256, 0, stream>>>(v, vT, f2f, W16);
    ffm_fused<<<B_ROWS / BM, 256, 0, stream>>>(X, W16, w1, b, out);
}

// Round 9
// 129.838 us; speedup vs baseline: 1.2393x; 1.2393x over previous
//
#include <hip/hip_runtime.h>
#include <hip/hip_bf16.h>
#include <math.h>

// FFM: B=32768, n=512, f=30, k=40
// inter[b] = X[b]^T W X[b],  W = 0.5*(C - diag(C)), C symmetric
// out = sigmoid(X@w1 + b + inter)
//
// R9: barrier-free K-loop with wave-PRIVATE Bs strips.
//  - As = 64x512 bf16 full-K, XOR-swizzled, staged once in Phase A (one barrier).
//  - Each wave stages its own 32-col x 64-K strip (4 KB) via global_load_lds
//    and syncs with per-wave s_waitcnt only -> ZERO __syncthreads in K-loop.
//  - Wave tile 64 rows x 32 cols (mi=4, ni=2). Linear term folded into the
//    epilogue (fp32 x from global, rs += x*(y + w1)).
//  - LDS = 64 + 16 = 80 KB exactly -> 2 blocks/CU. part[] aliases dead strips.

#define N_FEAT 512
#define FK 1200
#define KDIM 40
#define B_ROWS 32768
#define BM 64

typedef __attribute__((ext_vector_type(8))) short short8;
typedef __attribute__((ext_vector_type(4))) float f32x4;

__device__ __forceinline__ unsigned short bf16_rne(float f) {
    union { float f; unsigned int u; } c; c.f = f;
    unsigned int u = c.u;
    u += 0x7fffu + ((u >> 16) & 1u);
    return (unsigned short)(u >> 16);
}

__device__ __forceinline__ void async_copy16(const void* g, void* l) {
    __builtin_amdgcn_global_load_lds(
        (const __attribute__((address_space(1))) void*)g,
        (__attribute__((address_space(3))) void*)l,
        16, 0, 0);
}

// ---------------- Kernel 0: transpose v (512 x 1200) -> vT (1200 x 512) ----------------
__global__ __launch_bounds__(256) void transpose_v(const float* __restrict__ v,
                                                   float* __restrict__ vT) {
    const int c = blockIdx.x;           // 0..1199
    const int i0 = threadIdx.x;
    vT[(size_t)c * N_FEAT + i0]       = v[(size_t)i0 * FK + c];
    vT[(size_t)c * N_FEAT + i0 + 256] = v[(size_t)(i0 + 256) * FK + c];
}

// ---------------- Kernel 1: build W16 (512x512 bf16), coalesced ----------------
__global__ __launch_bounds__(256) void build_w16(const float* __restrict__ v,
                                                 const float* __restrict__ vT,
                                                 const int* __restrict__ f2f,
                                                 unsigned short* __restrict__ W16) {
    __shared__ float vi[FK];
    const int tid = threadIdx.x;
    const int i   = blockIdx.x;         // 0..511

    for (int c = tid; c < FK; c += 256)
        vi[c] = v[(size_t)i * FK + c];
    const int fi = f2f[i];
    const int j0 = tid;
    const int j1 = tid + 256;
    const int fj0 = f2f[j0];
    const int fj1 = f2f[j1];
    __syncthreads();

    const float* base = vT + (size_t)fi * KDIM * N_FEAT;
    float acc0 = 0.f, acc1 = 0.f;
#pragma unroll
    for (int q = 0; q < KDIM; ++q) {
        const float c0 = base[q * N_FEAT + j0];
        const float c1 = base[q * N_FEAT + j1];
        acc0 = fmaf(vi[fj0 * KDIM + q], c0, acc0);
        acc1 = fmaf(vi[fj1 * KDIM + q], c1, acc1);
    }
    W16[(size_t)i * N_FEAT + j0] = (i == j0) ? (unsigned short)0 : bf16_rne(0.5f * acc0);
    W16[(size_t)i * N_FEAT + j1] = (i == j1) ? (unsigned short)0 : bf16_rne(0.5f * acc1);
}

// ---------------- Kernel 2: fused GEMM + quadratic-form epilogue ----------------
// grid: 512 blocks x 256 threads (4 waves). Wave w: 64 rows x 32 cols
// (cols = cb*128 + w*32), private Bs strip, no K-loop barriers.
__global__ __launch_bounds__(256, 2) void ffm_fused(const float* __restrict__ X,
                                                    const unsigned short* __restrict__ W16,
                                                    const float* __restrict__ w1,
                                                    const float* __restrict__ bvec,
                                                    float* __restrict__ out) {
    __shared__ __align__(16) unsigned short As[BM * N_FEAT];   // 64 KB, swizzled
    __shared__ __align__(16) unsigned short Bs[4][32 * 64];    // 4 x 4 KB strips

    const int tid  = threadIdx.x;
    const int lane = tid & 63;
    const int wave = tid >> 6;
    const int quad = lane >> 4;
    const int l16  = lane & 15;
    const int aswz = l16 & 7;

    const size_t row0 = (size_t)blockIdx.x * BM;

    // ---- Phase A: stage As = bf16(X[row0:+64][0:512]), XOR-swizzled ----
    {
        const float4* X4 = (const float4*)(X + row0 * N_FEAT);
#pragma unroll
        for (int u = 0; u < 16; ++u) {
            const int r  = u * 4 + wave;    // wave-uniform row
            const int cc = lane;            // 16B chunk in row
            float4 f0 = X4[r * 128 + cc * 2];
            float4 f1 = X4[r * 128 + cc * 2 + 1];
            union { unsigned short us[8]; short8 v; } pk;
            pk.us[0] = bf16_rne(f0.x);
            pk.us[1] = bf16_rne(f0.y);
            pk.us[2] = bf16_rne(f0.z);
            pk.us[3] = bf16_rne(f0.w);
            pk.us[4] = bf16_rne(f1.x);
            pk.us[5] = bf16_rne(f1.y);
            pk.us[6] = bf16_rne(f1.z);
            pk.us[7] = bf16_rne(f1.w);
            *(short8*)(As + r * N_FEAT + ((cc ^ (r & 7)) << 3)) = pk.v;
        }
    }
    __syncthreads();   // As ready; the only barrier before the final reduction

    // staging coords (XOR preimage; LDS dest = wave-uniform base + lane*16)
    const int srow = lane >> 3;                     // 0..7 within 8-row chunk
    const int scol = (((lane & 7) ^ srow) << 3);    // source k-elem offset

    unsigned short* strip = &Bs[wave][0];

    float rs[4][4];
#pragma unroll
    for (int mi = 0; mi < 4; ++mi)
#pragma unroll
        for (int reg = 0; reg < 4; ++reg) rs[mi][reg] = 0.f;

    for (int cb = 0; cb < 4; ++cb) {
        const int colw = cb * 128 + wave * 32;

        f32x4 acc[4][2];
#pragma unroll
        for (int mi = 0; mi < 4; ++mi) {
            acc[mi][0] = (f32x4){0.f, 0.f, 0.f, 0.f};
            acc[mi][1] = (f32x4){0.f, 0.f, 0.f, 0.f};
        }

        for (int k0 = 0; k0 < N_FEAT; k0 += 64) {
            // WAR: prior step's ds_reads of this strip are complete
            asm volatile("s_waitcnt lgkmcnt(0)" ::: "memory");
#pragma unroll
            for (int c = 0; c < 4; ++c) {
                const int sr = c * 8 + srow;         // strip row 0..31
                async_copy16(W16 + (size_t)(colw + sr) * N_FEAT + k0 + scol,
                             strip + c * 512);
            }
            // per-wave drain: this wave's strip landed (no cross-wave dep)
            asm volatile("s_waitcnt vmcnt(0)" ::: "memory");

#pragma unroll
            for (int kk = 0; kk < 2; ++kk) {
                short8 a[4], b[2];
                const int kc  = (k0 >> 3) + kk * 4 + quad;
                const int off = (kc ^ aswz) << 3;
#pragma unroll
                for (int mi = 0; mi < 4; ++mi)
                    a[mi] = *(const short8*)(As + (mi * 16 + l16) * N_FEAT + off);
                const int swc = ((kk * 4 + quad) ^ aswz) << 3;
#pragma unroll
                for (int ni = 0; ni < 2; ++ni)
                    b[ni] = *(const short8*)(strip + (ni * 16 + l16) * 64 + swc);
#pragma unroll
                for (int mi = 0; mi < 4; ++mi)
#pragma unroll
                    for (int ni = 0; ni < 2; ++ni)
                        acc[mi][ni] = __builtin_amdgcn_mfma_f32_16x16x32_bf16(
                            a[mi], b[ni], acc[mi][ni], 0, 0, 0);
            }
        }

        // Epilogue: rs += x * (y + w1), x fp32 from global (coalesced over l16).
#pragma unroll
        for (int ni = 0; ni < 2; ++ni) {
            const int gc = colw + ni * 16 + l16;
            const float w1v = w1[gc];
#pragma unroll
            for (int mi = 0; mi < 4; ++mi)
#pragma unroll
                for (int reg = 0; reg < 4; ++reg) {
                    const int row = mi * 16 + quad * 4 + reg;
                    const float xv = X[(row0 + row) * N_FEAT + gc];
                    rs[mi][reg] = fmaf(xv, acc[mi][ni][reg] + w1v, rs[mi][reg]);
                }
        }
    }

    // ---- reduce over l16; stash per-wave row sums in own (dead) strip ----
    asm volatile("s_waitcnt lgkmcnt(0)" ::: "memory");
    float* fb = (float*)strip;     // 64 floats needed, 4 KB available
#pragma unroll
    for (int mi = 0; mi < 4; ++mi)
#pragma unroll
        for (int reg = 0; reg < 4; ++reg) {
            float r = rs[mi][reg];
#pragma unroll
            for (int off = 1; off < 16; off <<= 1)
                r += __shfl_xor(r, off, 16);
            if (l16 == 0)
                fb[mi * 16 + quad * 4 + reg] = r;
        }
    __syncthreads();

    if (tid < BM) {
        const float* f = (const float*)&Bs[0][0];   // strip stride = 1024 floats
        const float t = f[tid] + f[1024 + tid] + f[2048 + tid] + f[3072 + tid]
                        + bvec[0];
        out[row0 + tid] = 1.0f / (1.0f + expf(-t));
    }
}

extern "C" void kernel_launch(void* const* d_in, const int* in_sizes, int n_in,
                              void* d_out, int out_size, void* d_ws, size_t ws_size,
                              hipStream_t stream) {
    const float* X   = (const float*)d_in[0];   // 32768 x 512
    const float* w1  = (const float*)d_in[1];   // 512
    const float* b   = (const float*)d_in[2];   // 1
    const float* v   = (const float*)d_in[3];   // 512 x 30 x 40
    const int*   f2f = (const int*)d_in[4];     // 512
    float* out = (float*)d_out;                 // 32768

    unsigned short* W16 = (unsigned short*)d_ws;                  // 512 KB
    float*          vT  = (float*)((char*)d_ws + (1u << 20));     // 2.4 MB

    transpose_v<<<FK, 256, 0, stream>>>(v, vT);
    build_w16<<<N_FEAT, 256, 0, stream>>>(v, vT, f2f, W16);
    ffm_fused<<<B_ROWS / BM, 256, 0, stream>>>(X, W16, w1, b, out);
}